// Round 2
// baseline (475.076 us; speedup 1.0000x reference)
//
#include <hip/hip_runtime.h>
#include <hip/hip_bf16.h>
#include <stdint.h>

#define IN_F  2048
#define OUT_F 8192
#define NROW  8192
#define NIB   64      // in-blocks of 32
#define NOB   64      // out-blocks of 128
#define KSEL  410     // ceil(4096 * 0.1)

typedef __attribute__((ext_vector_type(8))) short  short8;
typedef __attribute__((ext_vector_type(4))) float  f32x4;

__device__ __forceinline__ unsigned short f2bf(float f) {
  unsigned u = __float_as_uint(f);
  unsigned r = (u + 0x7FFFu + ((u >> 16) & 1)) >> 16;   // RNE
  return (unsigned short)r;
}

__device__ __forceinline__ void gll16(const void* g, void* l) {
  __builtin_amdgcn_global_load_lds(
      (const __attribute__((address_space(1))) void*)g,
      (__attribute__((address_space(3))) void*)l, 16, 0, 0);
}

// ---------------- Kernel 1: block |W| sums in f64 --------------------------
// block b = p*64 + j : in-block p (32 cols), out-block j (128 rows)
__global__ __launch_bounds__(256) void pool_kernel(const float* __restrict__ W,
                                                   double* __restrict__ pooled) {
  int b = blockIdx.x;
  int p = b >> 6, j = b & 63;
  int t = threadIdx.x;
  int tr = t >> 3;            // 0..31
  int tc = (t & 7) * 4;       // 0..28
  const float* base = W + (size_t)(j * 128) * IN_F + p * 32;
  double s = 0.0;
#pragma unroll
  for (int ps = 0; ps < 4; ++ps) {
    float4 v = *(const float4*)(base + (size_t)(tr + 32 * ps) * IN_F + tc);
    s += fabs((double)v.x) + fabs((double)v.y) + fabs((double)v.z) + fabs((double)v.w);
  }
  for (int o = 32; o; o >>= 1) s += __shfl_down(s, o, 64);
  __shared__ double ws4[4];
  if ((t & 63) == 0) ws4[t >> 6] = s;
  __syncthreads();
  if (t == 0) pooled[b] = ws4[0] + ws4[1] + ws4[2] + ws4[3];
}

// ---------------- Kernel 2: top-k select + per-out-block lists -------------
__global__ __launch_bounds__(256) void topk_kernel(const double* __restrict__ pooled,
                                                   int* __restrict__ cnt,
                                                   int* __restrict__ lst) {
  __shared__ unsigned long long v[4096];
  __shared__ unsigned char keep[4096];
  __shared__ int red[4];
  __shared__ int pre[256];
  __shared__ int sq[1];
  int t = threadIdx.x;
  for (int i = t; i < 4096; i += 256) v[i] = (unsigned long long)__double_as_longlong(pooled[i]);
  __syncthreads();

  // binary search for T = bit pattern of 410th-largest (sums are >= 0)
  unsigned long long lo = 0, hi = ~0ull;
  while (lo < hi) {
    unsigned long long mid = lo + ((hi - lo) >> 1) + 1;
    int c = 0;
#pragma unroll 4
    for (int q = 0; q < 16; ++q) c += (v[t * 16 + q] >= mid) ? 1 : 0;
    for (int o = 32; o; o >>= 1) c += __shfl_down(c, o, 64);
    if ((t & 63) == 0) red[t >> 6] = c;
    __syncthreads();
    int tot = red[0] + red[1] + red[2] + red[3];
    __syncthreads();
    if (tot >= KSEL) lo = mid; else hi = mid - 1;
  }
  unsigned long long T = lo;

  int eqc = 0, gtc = 0;
#pragma unroll 4
  for (int q = 0; q < 16; ++q) {
    unsigned long long xv = v[t * 16 + q];
    eqc += (xv == T) ? 1 : 0;
    gtc += (xv > T) ? 1 : 0;
  }
  pre[t] = eqc;
  for (int o = 32; o; o >>= 1) gtc += __shfl_down(gtc, o, 64);
  if ((t & 63) == 0) red[t >> 6] = gtc;
  __syncthreads();
  if (t == 0) {
    int run = 0;
    for (int q = 0; q < 256; ++q) { int e = pre[q]; pre[q] = run; run += e; }
    sq[0] = red[0] + red[1] + red[2] + red[3];   // count strictly greater
  }
  __syncthreads();
  int quota = KSEL - sq[0];
  int run = pre[t];
  for (int q = 0; q < 16; ++q) {
    int i = t * 16 + q;
    unsigned long long xv = v[i];
    unsigned char kp = 0;
    if (xv > T) kp = 1;
    else if (xv == T) { kp = (run < quota) ? 1 : 0; ++run; }  // ties: lowest flat index first
    keep[i] = kp;
  }
  __syncthreads();
  if (t < 64) {                  // t = out-block j; flat index = ib*64 + j
    int c2 = 0;
    for (int ib = 0; ib < 64; ++ib)
      if (keep[ib * 64 + t]) { lst[t * 64 + c2] = ib; ++c2; }
    cnt[t] = c2;
  }
}

// ---------------- Kernel 3: convert active W blocks -> compact bf16 --------
// slot (j, s): 8KB tile [128 rows][32 k] row-major, contiguous
__global__ __launch_bounds__(256) void wcvt_kernel(const float* __restrict__ W,
                                                   const int* __restrict__ cnt,
                                                   const int* __restrict__ lst,
                                                   unsigned short* __restrict__ wbc) {
  int b = blockIdx.x;
  int j = b >> 6, s = b & 63;
  if (s >= cnt[j]) return;
  int ib = lst[j * 64 + s];
  int t = threadIdx.x;
  int tr = t >> 3, tc = (t & 7) * 4;
  const float* src = W + (size_t)(j * 128) * IN_F + ib * 32;
  unsigned short* dst = wbc + (size_t)(j * 64 + s) * 4096;
#pragma unroll
  for (int ps = 0; ps < 4; ++ps) {
    int r = tr + 32 * ps;
    float4 v = *(const float4*)(src + (size_t)r * IN_F + tc);
    unsigned short* o = dst + r * 32 + tc;
    o[0] = f2bf(v.x); o[1] = f2bf(v.y); o[2] = f2bf(v.z); o[3] = f2bf(v.w);
  }
}

// ---------------- Kernel 4: x f32 -> bf16 block-panel layout ---------------
// xb[(ib*8192 + row)*32 + k] : each (i-tile, ib) x-tile is 8KB contiguous
__global__ __launch_bounds__(256) void xcvt_kernel(const float* __restrict__ x,
                                                   unsigned short* __restrict__ xb) {
  int t = threadIdx.x;
  int row = blockIdx.x * 4 + (t >> 6);
  int ib = t & 63;
  const float* src = x + (size_t)row * IN_F + ib * 32;
  unsigned short* dst = xb + ((size_t)ib * NROW + row) * 32;
#pragma unroll
  for (int h = 0; h < 4; ++h) {
    float4 a = *(const float4*)(src + h * 8);
    float4 c = *(const float4*)(src + h * 8 + 4);
    short8 o;
    o[0] = (short)f2bf(a.x); o[1] = (short)f2bf(a.y);
    o[2] = (short)f2bf(a.z); o[3] = (short)f2bf(a.w);
    o[4] = (short)f2bf(c.x); o[5] = (short)f2bf(c.y);
    o[6] = (short)f2bf(c.z); o[7] = (short)f2bf(c.w);
    *(short8*)(dst + h * 8) = o;
  }
}

// ---------------- Kernel 5: block-sparse bf16 MFMA GEMM --------------------
// 128x128 tile, 4 waves (2x2), each wave 64x64 via 4x4 frags of 16x16x32
__global__ __launch_bounds__(256) void gemm_kernel(const unsigned short* __restrict__ xb,
                                                   const unsigned short* __restrict__ wbc,
                                                   const int* __restrict__ cnt,
                                                   const int* __restrict__ lst,
                                                   const float* __restrict__ bias,
                                                   float* __restrict__ C) {
  int b = blockIdx.x;
  int j = b & 63;           // out tile (== out-block)
  int i = b >> 6;           // row tile
  int t = threadIdx.x;
  int lane = t & 63, wv = t >> 6;
  int wr = wv >> 1, wc = wv & 1;
  int r = lane & 15, s = lane >> 4;

  __shared__ unsigned short lA[2][4096];   // [128][32] bf16, 8KB each
  __shared__ unsigned short lB[2][4096];

  int c = cnt[j];
  const int* mylst = lst + j * 64;

  f32x4 acc[4][4];
#pragma unroll
  for (int m = 0; m < 4; ++m)
#pragma unroll
    for (int n = 0; n < 4; ++n) acc[m][n] = {0.f, 0.f, 0.f, 0.f};

  auto stage = [&](int bufi, int kk) {
    int kb = mylst[kk];
    const char* gA = (const char*)(xb + ((size_t)kb * NROW + (size_t)i * 128) * 32);
    const char* gB = (const char*)(wbc + (size_t)(j * 64 + kk) * 4096);
    char* dA = (char*)&lA[bufi][0];
    char* dB = (char*)&lB[bufi][0];
    int c0 = t * 16;                 // (wv*64 + lane) * 16
    gll16(gA + c0,        dA + wv * 1024);
    gll16(gA + c0 + 4096, dA + wv * 1024 + 4096);
    gll16(gB + c0,        dB + wv * 1024);
    gll16(gB + c0 + 4096, dB + wv * 1024 + 4096);
  };

  auto compute = [&](int bufi) {
    short8 af[4], bf_[4];
#pragma unroll
    for (int m = 0; m < 4; ++m)
      af[m] = *(const short8*)&lA[bufi][(wr * 64 + m * 16 + r) * 32 + s * 8];
#pragma unroll
    for (int n = 0; n < 4; ++n)
      bf_[n] = *(const short8*)&lB[bufi][(wc * 64 + n * 16 + r) * 32 + s * 8];
#pragma unroll
    for (int m = 0; m < 4; ++m)
#pragma unroll
      for (int n = 0; n < 4; ++n)
        acc[m][n] = __builtin_amdgcn_mfma_f32_16x16x32_bf16(af[m], bf_[n], acc[m][n], 0, 0, 0);
  };

  if (c > 0) stage(0, 0);
  __syncthreads();                       // drains vmcnt -> buf0 ready
  for (int kk = 0; kk < c; ++kk) {
    if (kk + 1 < c) stage((kk + 1) & 1, kk + 1);   // prefetch into other buffer
    compute(kk & 1);
    __syncthreads();                     // drains vmcnt -> next buffer ready
  }

  // epilogue: C/D layout col = lane&15, row = (lane>>4)*4 + reg  [m89-verified]
  float bv[4];
#pragma unroll
  for (int n = 0; n < 4; ++n) bv[n] = bias[j * 128 + wc * 64 + n * 16 + r];
#pragma unroll
  for (int m = 0; m < 4; ++m) {
    int row0 = i * 128 + wr * 64 + m * 16 + s * 4;
#pragma unroll
    for (int n = 0; n < 4; ++n) {
      int col = j * 128 + wc * 64 + n * 16 + r;
#pragma unroll
      for (int q = 0; q < 4; ++q)
        C[(size_t)(row0 + q) * OUT_F + col] = acc[m][n][q] + bv[n];
    }
  }
}

extern "C" void kernel_launch(void* const* d_in, const int* in_sizes, int n_in,
                              void* d_out, int out_size, void* d_ws, size_t ws_size,
                              hipStream_t stream) {
  const float* x    = (const float*)d_in[0];
  const float* W    = (const float*)d_in[1];
  const float* bias = (const float*)d_in[2];
  float* out        = (float*)d_out;
  char* ws          = (char*)d_ws;

  // ws layout: pooled f64 [32KB] | cnt [1KB pad] | lst [32KB pad] | wbc 32MB | xb 32MB
  double* pooled      = (double*)ws;
  int*    cntp        = (int*)(ws + 32768);
  int*    lstp        = (int*)(ws + 32768 + 1024);
  unsigned short* wbc = (unsigned short*)(ws + 65536);
  unsigned short* xb  = (unsigned short*)(ws + 65536 + (size_t)NOB * 64 * 4096 * 2);

  hipLaunchKernelGGL(pool_kernel, dim3(4096), dim3(256), 0, stream, W, pooled);
  hipLaunchKernelGGL(topk_kernel, dim3(1),    dim3(256), 0, stream, pooled, cntp, lstp);
  hipLaunchKernelGGL(wcvt_kernel, dim3(4096), dim3(256), 0, stream, W, cntp, lstp, wbc);
  hipLaunchKernelGGL(xcvt_kernel, dim3(2048), dim3(256), 0, stream, x, xb);
  hipLaunchKernelGGL(gemm_kernel, dim3(4096), dim3(256), 0, stream, xb, wbc, cntp, lstp, bias, out);
}

// Round 3
// 460.730 us; speedup vs baseline: 1.0311x; 1.0311x over previous
//
#include <hip/hip_runtime.h>
#include <hip/hip_bf16.h>
#include <stdint.h>

#define IN_F  2048
#define OUT_F 8192
#define NROW  8192
#define KSEL  410     // ceil(4096 * 0.1)

typedef __attribute__((ext_vector_type(8))) short  short8;
typedef __attribute__((ext_vector_type(4))) short  short4v;
typedef __attribute__((ext_vector_type(4))) float  f32x4;

__device__ __forceinline__ unsigned short f2bf(float f) {
  unsigned u = __float_as_uint(f);
  unsigned r = (u + 0x7FFFu + ((u >> 16) & 1)) >> 16;   // RNE
  return (unsigned short)r;
}

__device__ __forceinline__ void gll16(const void* g, void* l) {
  __builtin_amdgcn_global_load_lds(
      (const __attribute__((address_space(1))) void*)g,
      (__attribute__((address_space(3))) void*)l, 16, 0, 0);
}

// ---- Kernel 1: fused W pool (f64 abs-sum) + f32->bf16 row-major convert ----
// block b: p = b>>6 in-block (32 cols), j = b&63 out-block (128 rows)
__global__ __launch_bounds__(256) void prep_w(const float* __restrict__ W,
                                              unsigned short* __restrict__ Wb,
                                              double* __restrict__ pooled) {
  int b = blockIdx.x;
  int p = b >> 6, j = b & 63;
  int t = threadIdx.x;
  int tr = t >> 3;            // 0..31 row within 32-row pass
  int tc = (t & 7) * 4;       // 0..28 col
  const float*    src = W  + (size_t)(j * 128) * IN_F + p * 32;
  unsigned short* dst = Wb + (size_t)(j * 128) * IN_F + p * 32;
  double s = 0.0;
#pragma unroll
  for (int ps = 0; ps < 4; ++ps) {
    int r = tr + 32 * ps;
    float4 v = *(const float4*)(src + (size_t)r * IN_F + tc);
    s += fabs((double)v.x) + fabs((double)v.y) + fabs((double)v.z) + fabs((double)v.w);
    short4v o;
    o[0] = (short)f2bf(v.x); o[1] = (short)f2bf(v.y);
    o[2] = (short)f2bf(v.z); o[3] = (short)f2bf(v.w);
    *(short4v*)(dst + (size_t)r * IN_F + tc) = o;     // 8B coalesced
  }
  for (int o = 32; o; o >>= 1) s += __shfl_down(s, o, 64);
  __shared__ double ws4[4];
  if ((t & 63) == 0) ws4[t >> 6] = s;
  __syncthreads();
  if (t == 0) pooled[b] = ws4[0] + ws4[1] + ws4[2] + ws4[3];
}

// ---- Kernel 2: x f32 -> bf16, row-major, fully coalesced ----
__global__ __launch_bounds__(256) void xcvt(const float* __restrict__ x,
                                            unsigned short* __restrict__ xb) {
  size_t base = (size_t)blockIdx.x * 2048;
  int t = threadIdx.x;
  float4 a = *(const float4*)(x + base + t * 4);
  float4 c = *(const float4*)(x + base + 1024 + t * 4);
  short4v o1, o2;
  o1[0] = (short)f2bf(a.x); o1[1] = (short)f2bf(a.y);
  o1[2] = (short)f2bf(a.z); o1[3] = (short)f2bf(a.w);
  o2[0] = (short)f2bf(c.x); o2[1] = (short)f2bf(c.y);
  o2[2] = (short)f2bf(c.z); o2[3] = (short)f2bf(c.w);
  *(short4v*)(xb + base + t * 4) = o1;
  *(short4v*)(xb + base + 1024 + t * 4) = o2;
}

// ---- Kernel 3: exact top-410 via 8-round byte radix-select ----
// T = 410th-largest u64 key (positive f64 bits are order-preserving);
// quota `need` among keys == T, taken in lowest-flat-index order (jax tie rule).
__global__ __launch_bounds__(256) void topk_kernel(const double* __restrict__ pooled,
                                                   int* __restrict__ cnt,
                                                   int* __restrict__ lst) {
  __shared__ int hist[4][256];
  __shared__ unsigned long long bcast;
  __shared__ int ineed;
  __shared__ unsigned char keep[4096];
  __shared__ int pre[256];
  int t = threadIdx.x;
  int wv = t >> 6;
  unsigned long long key[16];
#pragma unroll
  for (int q = 0; q < 16; ++q)
    key[q] = (unsigned long long)__double_as_longlong(pooled[t * 16 + q]);

  unsigned long long prefix = 0;
  int need = KSEL;
  for (int byte = 7; byte >= 0; --byte) {
    int sh = byte * 8;
    unsigned long long maskhi = (byte == 7) ? 0ull : (~0ull << (sh + 8));
    hist[0][t] = 0; hist[1][t] = 0; hist[2][t] = 0; hist[3][t] = 0;
    __syncthreads();
#pragma unroll
    for (int q = 0; q < 16; ++q) {
      unsigned long long k = key[q];
      if ((k & maskhi) == (prefix & maskhi))
        atomicAdd(&hist[wv][(int)((k >> sh) & 255)], 1);
    }
    __syncthreads();
    if (t < 64) {
      int h[4]; int own = 0;
#pragma unroll
      for (int b2 = 0; b2 < 4; ++b2) {
        h[b2] = hist[0][t*4+b2] + hist[1][t*4+b2] + hist[2][t*4+b2] + hist[3][t*4+b2];
        own += h[b2];
      }
      int s = own;                         // inclusive suffix over lanes
#pragma unroll
      for (int off = 1; off < 64; off <<= 1) {
        int tmp = __shfl_down(s, off, 64);
        if (t + off < 64) s += tmp;
      }
      int cum = s - own;                   // keys in bins above this lane's bins
#pragma unroll
      for (int b2 = 3; b2 >= 0; --b2) {
        if (cum < need && need <= cum + h[b2]) {   // exactly one (lane,bin) hits
          bcast = prefix | ((unsigned long long)(t * 4 + b2) << sh);
          ineed = need - cum;
        }
        cum += h[b2];
      }
    }
    __syncthreads();
    prefix = bcast;
    need = ineed;
    __syncthreads();
  }
  unsigned long long T = prefix;
  int quota = need;                        // # of ==T keys to keep

  int eqc = 0;
#pragma unroll
  for (int q = 0; q < 16; ++q) eqc += (key[q] == T) ? 1 : 0;
  pre[t] = eqc;
  __syncthreads();
  if (t == 0) {
    int run = 0;
    for (int q = 0; q < 256; ++q) { int e = pre[q]; pre[q] = run; run += e; }
  }
  __syncthreads();
  int run = pre[t];
#pragma unroll
  for (int q = 0; q < 16; ++q) {
    unsigned long long k = key[q];
    unsigned char kp = 0;
    if (k > T) kp = 1;
    else if (k == T) { kp = (run < quota) ? 1 : 0; ++run; }
    keep[t * 16 + q] = kp;
  }
  __syncthreads();
  if (t < 64) {                  // t = out-block j; flat pooled index = ib*64 + j
    int c2 = 0;
    for (int ib = 0; ib < 64; ++ib)
      if (keep[ib * 64 + t]) { lst[t * 64 + c2] = ib; ++c2; }
    cnt[t] = c2;
  }
}

// ---- Kernel 4: block-sparse bf16 MFMA GEMM, row-major operands ----
// 128x128 tile, 4 waves (2x2), each wave 64x64 via 4x4 frags of 16x16x32.
// Staging: global_load_lds w=16, per-lane SOURCE addressing from row-major
// bf16 (row stride 4096B), linear LDS dest [128][32] bf16 (64B rows).
__global__ __launch_bounds__(256) void gemm_kernel(const unsigned short* __restrict__ xb,
                                                   const unsigned short* __restrict__ Wb,
                                                   const int* __restrict__ cnt,
                                                   const int* __restrict__ lst,
                                                   const float* __restrict__ bias,
                                                   float* __restrict__ C) {
  int b0 = blockIdx.x;
  int w = ((b0 & 7) << 9) | (b0 >> 3);    // XCD swizzle: 4096 = 8 XCD * 512
  int i = w >> 6, j = w & 63;
  int t = threadIdx.x;
  int lane = t & 63, wv = t >> 6;
  int wr = wv >> 1, wc = wv & 1;
  int r = lane & 15, s = lane >> 4;

  __shared__ unsigned short lA[2][4096];   // [128][32] bf16, 8KB
  __shared__ unsigned short lB[2][4096];

  int c = cnt[j];
  const int* mylst = lst + j * 64;

  f32x4 acc[4][4];
#pragma unroll
  for (int m = 0; m < 4; ++m)
#pragma unroll
    for (int n = 0; n < 4; ++n) acc[m][n] = {0.f, 0.f, 0.f, 0.f};

  int trow = t >> 2, tcb = t & 3;         // lane row 0..63, 16B chunk 0..3
  const char* xbase = (const char*)xb + (size_t)(i * 128 + trow) * (IN_F * 2) + tcb * 16;
  const char* wbase = (const char*)Wb + (size_t)(j * 128 + trow) * (IN_F * 2) + tcb * 16;

  auto stage = [&](int bufi, int kk) {
    int kb = mylst[kk];
    const char* gA = xbase + kb * 64;
    const char* gB = wbase + kb * 64;
    char* dA = (char*)&lA[bufi][0] + t * 16;
    char* dB = (char*)&lB[bufi][0] + t * 16;
    gll16(gA,                          dA);
    gll16(gA + (size_t)64 * IN_F * 2,  dA + 4096);   // rows 64..127
    gll16(gB,                          dB);
    gll16(gB + (size_t)64 * IN_F * 2,  dB + 4096);
  };

  auto compute = [&](int bufi) {
    short8 af[4], bf_[4];
#pragma unroll
    for (int m = 0; m < 4; ++m)
      af[m] = *(const short8*)&lA[bufi][(wr * 64 + m * 16 + r) * 32 + s * 8];
#pragma unroll
    for (int n = 0; n < 4; ++n)
      bf_[n] = *(const short8*)&lB[bufi][(wc * 64 + n * 16 + r) * 32 + s * 8];
#pragma unroll
    for (int m = 0; m < 4; ++m)
#pragma unroll
      for (int n = 0; n < 4; ++n)
        acc[m][n] = __builtin_amdgcn_mfma_f32_16x16x32_bf16(af[m], bf_[n], acc[m][n], 0, 0, 0);
  };

  if (c > 0) stage(0, 0);
  __syncthreads();                       // drains vmcnt -> buf0 ready
  for (int kk = 0; kk < c; ++kk) {
    if (kk + 1 < c) stage((kk + 1) & 1, kk + 1);
    compute(kk & 1);
    __syncthreads();
  }

  // epilogue: C/D layout col = lane&15, row = (lane>>4)*4 + reg [m89-verified]
  float bv[4];
#pragma unroll
  for (int n = 0; n < 4; ++n) bv[n] = bias[j * 128 + wc * 64 + n * 16 + r];
#pragma unroll
  for (int m = 0; m < 4; ++m) {
    int row0 = i * 128 + wr * 64 + m * 16 + s * 4;
#pragma unroll
    for (int n = 0; n < 4; ++n) {
      int col = j * 128 + wc * 64 + n * 16 + r;
#pragma unroll
      for (int q = 0; q < 4; ++q)
        C[(size_t)(row0 + q) * OUT_F + col] = acc[m][n][q] + bv[n];
    }
  }
}

extern "C" void kernel_launch(void* const* d_in, const int* in_sizes, int n_in,
                              void* d_out, int out_size, void* d_ws, size_t ws_size,
                              hipStream_t stream) {
  const float* x    = (const float*)d_in[0];
  const float* W    = (const float*)d_in[1];
  const float* bias = (const float*)d_in[2];
  float* out        = (float*)d_out;
  char* ws          = (char*)d_ws;

  // ws: pooled f64 32KB | cnt 1KB | lst 31KB | Wb 32MB | xb 32MB
  double* pooled      = (double*)ws;
  int*    cntp        = (int*)(ws + 32768);
  int*    lstp        = (int*)(ws + 32768 + 1024);
  unsigned short* Wbp = (unsigned short*)(ws + 65536);
  unsigned short* xbp = (unsigned short*)(ws + 65536 + (size_t)OUT_F * IN_F * 2);

  hipLaunchKernelGGL(prep_w,      dim3(4096), dim3(256), 0, stream, W, Wbp, pooled);
  hipLaunchKernelGGL(xcvt,        dim3(8192), dim3(256), 0, stream, x, xbp);
  hipLaunchKernelGGL(topk_kernel, dim3(1),    dim3(256), 0, stream, pooled, cntp, lstp);
  hipLaunchKernelGGL(gemm_kernel, dim3(4096), dim3(256), 0, stream, xbp, Wbp, cntp, lstp, bias, out);
}